// Round 20
// baseline (273.813 us; speedup 1.0000x reference)
//
#include <hip/hip_runtime.h>
#include <stdint.h>

typedef __attribute__((ext_vector_type(8))) short short8;
typedef __attribute__((ext_vector_type(4))) float f32x4;

constexpr int      BATCH    = 524288;
constexpr int      ARRAY_SZ = 262144;
constexpr uint64_t PRIME    = 2038074743ull;
constexpr uint32_t RANGE    = 262137u;          // ARRAY_SZ - 8 + 1
constexpr int      NMT      = BATCH / 16;       // 32768 M-tiles of 16 elements
// Sign-certainty bound, 2-split (hi+mid) MFMA vs sequential-fmaf reference
// (derivation r17, verified absmax 0.0 r17-r19): total error < 5.4e-5 *
// Sum|x|, margin EPS = 8e-5. Flagged entries recomputed with the sequential
// fmaf chain proven bit-exact in rounds 1-19.
constexpr float    EPS      = 8e-5f;

__device__ __forceinline__ float fallback_proj(const float* __restrict__ xr,
                                               const unsigned short* T, int k)
{
    float s = 0.0f;
#pragma unroll 4
    for (int i8 = 0; i8 < 16; ++i8) {
        const uint4 tb = *reinterpret_cast<const uint4*>(
            &T[k * 128 + ((i8 ^ (k & 15)) << 3)]);
        const f32x4 xA = *reinterpret_cast<const f32x4*>(xr + i8 * 8);
        const f32x4 xB = *reinterpret_cast<const f32x4*>(xr + i8 * 8 + 4);
        const uint32_t tu[4] = {tb.x, tb.y, tb.z, tb.w};
        s = __builtin_fmaf(xA[0], __uint_as_float(tu[0] << 16), s);
        s = __builtin_fmaf(xA[1], __uint_as_float(tu[0] & 0xFFFF0000u), s);
        s = __builtin_fmaf(xA[2], __uint_as_float(tu[1] << 16), s);
        s = __builtin_fmaf(xA[3], __uint_as_float(tu[1] & 0xFFFF0000u), s);
        s = __builtin_fmaf(xB[0], __uint_as_float(tu[2] << 16), s);
        s = __builtin_fmaf(xB[1], __uint_as_float(tu[2] & 0xFFFF0000u), s);
        s = __builtin_fmaf(xB[2], __uint_as_float(tu[3] << 16), s);
        s = __builtin_fmaf(xB[3], __uint_as_float(tu[3] & 0xFFFF0000u), s);
    }
    return s;
}

__global__ __launch_bounds__(512, 2)
void lma_mfmaB(const float* __restrict__ x,
               const float* __restrict__ hw,
               const float* __restrict__ lsh,
               const void* __restrict__ rnd_raw,
               float* __restrict__ out_idx,   // B*128 floats (idx as f32)
               float* __restrict__ out_val)   // B*64 floats
{
    // ONLY LDS use: T[n][i] = lsh^T as bf16 (exact: {-1,0,1}); 16B-unit XOR
    // swizzle (proven r10-r19). 32768 B, shared by 8 waves.
    __shared__ unsigned short T[128 * 128];

    const int tid  = threadIdx.x;
    const int lane = tid & 63;
    const int wid  = __builtin_amdgcn_readfirstlane(tid >> 6);   // 0..7

    // --- hash constants: detect int64 vs int32 layout of random_numbers ---
    uint64_t HA, HB, HC0;
    {
        const uint64_t first8 = *reinterpret_cast<const uint64_t*>(rnd_raw);
        if (first8 == PRIME) {
            const long long* r64 = reinterpret_cast<const long long*>(rnd_raw);
            HA = (uint64_t)r64[1]; HB = (uint64_t)r64[2]; HC0 = (uint64_t)r64[3];
        } else {
            const int* r32 = reinterpret_cast<const int*>(rnd_raw);
            HA  = (uint64_t)(uint32_t)r32[1];
            HB  = (uint64_t)(uint32_t)r32[2];
            HC0 = (uint64_t)(uint32_t)r32[3];
        }
    }

    // --- stage T = bf16(lsh)^T, XOR-swizzled (one-time; 512 threads) ---
    for (int it = 0; it < 8; ++it) {
        const int flat4 = it * 512 + tid;            // 0..4095
        const int i  = flat4 >> 5;                   // input dim 0..127
        const int n4 = (flat4 & 31) << 2;            // output col base
        const f32x4 v = *reinterpret_cast<const f32x4*>(lsh + i * 128 + n4);
#pragma unroll
        for (int d = 0; d < 4; ++d) {
            const int n = n4 + d;
            T[n * 128 + (((i >> 3) ^ (n & 15)) << 3) + (i & 7)] =
                (unsigned short)(__float_as_uint(v[d]) >> 16);
        }
    }
    __syncthreads();   // only block barrier; T read-only afterwards

    const int r    = lane & 15;       // A/B fragment row (x row, T col)
    const int g    = lane >> 4;       // k-group
    const int e    = lane >> 2;       // phase-2 element (0..15)
    const int c4   = lane & 3;        // phase-2 chunk slot
    const int hf   = c4 & 1;          // col-half within a 16-col n8 block
    const int npar = c4 >> 1;         // n8 parity this lane consumes
    const int shb  = 16 * (e >> 2) + 8 * hf;   // bit offset in ballots
    const int sel  = e & 3;           // which reg's ballot holds row e
    const bool s0 = (sel == 0), s1 = (sel == 1), s2 = (sel == 2);
    const uint64_t hcc0 = HB * (uint64_t)c4 + HC0;        // chunks c4, c4 (m even)
    const uint64_t hcc1 = HB * (uint64_t)(c4 + 4) + HC0;  // chunks c4+4 (m odd)

    // ---- each wave owns TWO ADJACENT tiles, processed as one interleaved
    //      dual-stream body (2x ILP per wave: every latency has a twin) ----
    const int gw  = blockIdx.x * 8 + wid;        // 0..16383
    const int mtA = gw * 2;                      // 0..32766
    const int mtB = mtA + 1;

    // ---- load x fragments for BOTH tiles (16 dwordx4 in flight) ----
    f32x4 a0, a1, a2, a3, a4, a5, a6, a7;
    f32x4 b0, b1, b2, b3, b4, b5, b6, b7;
    {
        const float* xnA = x + (size_t)mtA * 16 * 128 + r * 128 + g * 8;
        const float* xnB = xnA + 16 * 128;
        a0 = *reinterpret_cast<const f32x4*>(xnA);
        a1 = *reinterpret_cast<const f32x4*>(xnA + 4);
        a2 = *reinterpret_cast<const f32x4*>(xnA + 32);
        a3 = *reinterpret_cast<const f32x4*>(xnA + 36);
        a4 = *reinterpret_cast<const f32x4*>(xnA + 64);
        a5 = *reinterpret_cast<const f32x4*>(xnA + 68);
        a6 = *reinterpret_cast<const f32x4*>(xnA + 96);
        a7 = *reinterpret_cast<const f32x4*>(xnA + 100);
        b0 = *reinterpret_cast<const f32x4*>(xnB);
        b1 = *reinterpret_cast<const f32x4*>(xnB + 4);
        b2 = *reinterpret_cast<const f32x4*>(xnB + 32);
        b3 = *reinterpret_cast<const f32x4*>(xnB + 36);
        b4 = *reinterpret_cast<const f32x4*>(xnB + 64);
        b5 = *reinterpret_cast<const f32x4*>(xnB + 68);
        b6 = *reinterpret_cast<const f32x4*>(xnB + 96);
        b7 = *reinterpret_cast<const f32x4*>(xnB + 100);
    }

    f32x4 accA[8], accB[8];
#pragma unroll
    for (int n8 = 0; n8 < 8; ++n8) { accA[n8] = (f32x4)(0.0f); accB[n8] = (f32x4)(0.0f); }
    float asumA = 0.0f, asumB = 0.0f;

    // ---- phase 1: exact 2-way split MFMA for BOTH tiles; one shared T read
    //      feeds 4 MFMAs (2 per tile) -> LDS traffic halved ----
#pragma unroll
    for (int ks = 0; ks < 4; ++ks) {
        const f32x4 xaA = (ks == 0) ? a0 : (ks == 1) ? a2 : (ks == 2) ? a4 : a6;
        const f32x4 xcA = (ks == 0) ? a1 : (ks == 1) ? a3 : (ks == 2) ? a5 : a7;
        const f32x4 xaB = (ks == 0) ? b0 : (ks == 1) ? b2 : (ks == 2) ? b4 : b6;
        const f32x4 xcB = (ks == 0) ? b1 : (ks == 1) ? b3 : (ks == 2) ? b5 : b7;
        float xsA[8] = {xaA[0], xaA[1], xaA[2], xaA[3], xcA[0], xcA[1], xcA[2], xcA[3]};
        float xsB[8] = {xaB[0], xaB[1], xaB[2], xaB[3], xcB[0], xcB[1], xcB[2], xcB[3]};
#pragma unroll
        for (int j = 0; j < 8; ++j) { asumA += fabsf(xsA[j]); asumB += fabsf(xsB[j]); }

        union { uint32_t u[4]; short8 v; } AhiA, AmiA, AhiB, AmiB;
#pragma unroll
        for (int p = 0; p < 4; ++p) {
            {
                const uint32_t b0_ = __float_as_uint(xsA[2 * p]);
                const uint32_t b1_ = __float_as_uint(xsA[2 * p + 1]);
                const uint32_t h0 = b0_ & 0xFFFF0000u, h1 = b1_ & 0xFFFF0000u;
                const float    t0 = xsA[2 * p] - __uint_as_float(h0);
                const float    t1 = xsA[2 * p + 1] - __uint_as_float(h1);
                const uint32_t m0 = __float_as_uint(t0) & 0xFFFF0000u;
                const uint32_t m1 = __float_as_uint(t1) & 0xFFFF0000u;
                AhiA.u[p] = h1 | (h0 >> 16);
                AmiA.u[p] = m1 | (m0 >> 16);
            }
            {
                const uint32_t b0_ = __float_as_uint(xsB[2 * p]);
                const uint32_t b1_ = __float_as_uint(xsB[2 * p + 1]);
                const uint32_t h0 = b0_ & 0xFFFF0000u, h1 = b1_ & 0xFFFF0000u;
                const float    t0 = xsB[2 * p] - __uint_as_float(h0);
                const float    t1 = xsB[2 * p + 1] - __uint_as_float(h1);
                const uint32_t m0 = __float_as_uint(t0) & 0xFFFF0000u;
                const uint32_t m1 = __float_as_uint(t1) & 0xFFFF0000u;
                AhiB.u[p] = h1 | (h0 >> 16);
                AmiB.u[p] = m1 | (m0 >> 16);
            }
        }
#pragma unroll
        for (int n8 = 0; n8 < 8; ++n8) {
            const short8 bf = *reinterpret_cast<const short8*>(
                &T[(n8 * 16 + r) * 128 + (((ks * 4 + g) ^ r) << 3)]);
            accA[n8] = __builtin_amdgcn_mfma_f32_16x16x32_bf16(AhiA.v, bf, accA[n8], 0, 0, 0);
            accA[n8] = __builtin_amdgcn_mfma_f32_16x16x32_bf16(AmiA.v, bf, accA[n8], 0, 0, 0);
            accB[n8] = __builtin_amdgcn_mfma_f32_16x16x32_bf16(AhiB.v, bf, accB[n8], 0, 0, 0);
            accB[n8] = __builtin_amdgcn_mfma_f32_16x16x32_bf16(AmiB.v, bf, accB[n8], 0, 0, 0);
        }
    }

    // ---- per-row |x| bounds for both tiles ----
    asumA += __shfl_xor(asumA, 16);  asumA += __shfl_xor(asumA, 32);
    asumB += __shfl_xor(asumB, 16);  asumB += __shfl_xor(asumB, 32);
    float bndrA[4], bndrB[4];
#pragma unroll
    for (int reg = 0; reg < 4; ++reg) {
        bndrA[reg] = __shfl(asumA, (lane >> 4) * 4 + reg) * EPS;
        bndrB[reg] = __shfl(asumB, (lane >> 4) * 4 + reg) * EPS;
    }

    // ---- ballot bit-transpose, both tiles (verbatim r18/r19 logic) ----
    uint32_t wsrpA = 0, wflgA = 0, wsrpB = 0, wflgB = 0;
#pragma unroll
    for (int n8 = 0; n8 < 8; ++n8) {
        const unsigned long long sA0 = __ballot(accA[n8][0] > 0.0f);
        const unsigned long long sA1 = __ballot(accA[n8][1] > 0.0f);
        const unsigned long long sA2 = __ballot(accA[n8][2] > 0.0f);
        const unsigned long long sA3 = __ballot(accA[n8][3] > 0.0f);
        const unsigned long long fA0 = __ballot(fabsf(accA[n8][0]) <= bndrA[0]);
        const unsigned long long fA1 = __ballot(fabsf(accA[n8][1]) <= bndrA[1]);
        const unsigned long long fA2 = __ballot(fabsf(accA[n8][2]) <= bndrA[2]);
        const unsigned long long fA3 = __ballot(fabsf(accA[n8][3]) <= bndrA[3]);
        const unsigned long long sB0 = __ballot(accB[n8][0] > 0.0f);
        const unsigned long long sB1 = __ballot(accB[n8][1] > 0.0f);
        const unsigned long long sB2 = __ballot(accB[n8][2] > 0.0f);
        const unsigned long long sB3 = __ballot(accB[n8][3] > 0.0f);
        const unsigned long long fB0 = __ballot(fabsf(accB[n8][0]) <= bndrB[0]);
        const unsigned long long fB1 = __ballot(fabsf(accB[n8][1]) <= bndrB[1]);
        const unsigned long long fB2 = __ballot(fabsf(accB[n8][2]) <= bndrB[2]);
        const unsigned long long fB3 = __ballot(fabsf(accB[n8][3]) <= bndrB[3]);
        if ((n8 & 1) == npar) {
            const unsigned long long sxA = s0 ? sA0 : s1 ? sA1 : s2 ? sA2 : sA3;
            const unsigned long long fxA = s0 ? fA0 : s1 ? fA1 : s2 ? fA2 : fA3;
            const unsigned long long sxB = s0 ? sB0 : s1 ? sB1 : s2 ? sB2 : sB3;
            const unsigned long long fxB = s0 ? fB0 : s1 ? fB1 : s2 ? fB2 : fB3;
            const int mshift = ((n8 - npar) >> 1) * 8;
            wsrpA |= (uint32_t)((sxA >> shb) & 0xffull) << mshift;
            wflgA |= (uint32_t)((fxA >> shb) & 0xffull) << mshift;
            wsrpB |= (uint32_t)((sxB >> shb) & 0xffull) << mshift;
            wflgB |= (uint32_t)((fxB >> shb) & 0xffull) << mshift;
        }
    }

    const size_t egA = (size_t)(mtA * 16 + e);
    const size_t egB = (size_t)(mtB * 16 + e);
    uint32_t locA[4], locB[4];

    // ---- hash + fallback + out_idx, tile A then tile B ----
#pragma unroll
    for (int m = 0; m < 4; ++m) {
        const int cc = c4 + 4 * m;
        uint32_t srp = (wsrpA >> (8 * m)) & 0xFFu;
        const uint32_t flg = (wflgA >> (8 * m)) & 0xFFu;
        if (flg) {
            const float* xr = x + egA * 128;
            for (uint32_t fb = flg; fb; fb &= fb - 1) {
                const int j = __builtin_ctz(fb);
                const float s = fallback_proj(xr, T, cc * 8 + j);
                srp = (srp & ~(1u << j)) | ((s > 0.0f) ? (1u << j) : 0u);
            }
        }
        const uint64_t hh  = (HA * (uint64_t)srp + ((m & 1) ? hcc1 : hcc0)) % PRIME;
        const uint32_t loc = (uint32_t)hh % RANGE + ((cc >> 3) ? (uint32_t)ARRAY_SZ : 0u);
        locA[m] = loc;
        const float f0 = (float)loc;
        float* oi = out_idx + egA * 128 + cc * 8;
        *reinterpret_cast<f32x4*>(oi)     = (f32x4){f0, f0 + 1.f, f0 + 2.f, f0 + 3.f};
        *reinterpret_cast<f32x4*>(oi + 4) = (f32x4){f0 + 4.f, f0 + 5.f, f0 + 6.f, f0 + 7.f};
    }
#pragma unroll
    for (int m = 0; m < 4; ++m) {
        const int cc = c4 + 4 * m;
        uint32_t srp = (wsrpB >> (8 * m)) & 0xFFu;
        const uint32_t flg = (wflgB >> (8 * m)) & 0xFFu;
        if (flg) {
            const float* xr = x + egB * 128;
            for (uint32_t fb = flg; fb; fb &= fb - 1) {
                const int j = __builtin_ctz(fb);
                const float s = fallback_proj(xr, T, cc * 8 + j);
                srp = (srp & ~(1u << j)) | ((s > 0.0f) ? (1u << j) : 0u);
            }
        }
        const uint64_t hh  = (HA * (uint64_t)srp + ((m & 1) ? hcc1 : hcc0)) % PRIME;
        const uint32_t loc = (uint32_t)hh % RANGE + ((cc >> 3) ? (uint32_t)ARRAY_SZ : 0u);
        locB[m] = loc;
        const float f0 = (float)loc;
        float* oi = out_idx + egB * 128 + cc * 8;
        *reinterpret_cast<f32x4*>(oi)     = (f32x4){f0, f0 + 1.f, f0 + 2.f, f0 + 3.f};
        *reinterpret_cast<f32x4*>(oi + 4) = (f32x4){f0 + 4.f, f0 + 5.f, f0 + 6.f, f0 + 7.f};
    }

    // ---- all 64 gathers issued back-to-back (max MLP), then consumed ----
    float wvA[4][8], wvB[4][8];
#pragma unroll
    for (int m = 0; m < 4; ++m)
#pragma unroll
        for (int j = 0; j < 8; ++j) wvA[m][j] = hw[locA[m] + j];
#pragma unroll
    for (int m = 0; m < 4; ++m)
#pragma unroll
        for (int j = 0; j < 8; ++j) wvB[m][j] = hw[locB[m] + j];

#pragma unroll
    for (int m = 0; m < 2; ++m) {
        float* ov = out_val + egA * 64 + (c4 + 4 * m) * 8;
        *reinterpret_cast<f32x4*>(ov) =
            (f32x4){(wvA[m][0] + wvA[2 + m][0]) * 0.5f, (wvA[m][1] + wvA[2 + m][1]) * 0.5f,
                    (wvA[m][2] + wvA[2 + m][2]) * 0.5f, (wvA[m][3] + wvA[2 + m][3]) * 0.5f};
        *reinterpret_cast<f32x4*>(ov + 4) =
            (f32x4){(wvA[m][4] + wvA[2 + m][4]) * 0.5f, (wvA[m][5] + wvA[2 + m][5]) * 0.5f,
                    (wvA[m][6] + wvA[2 + m][6]) * 0.5f, (wvA[m][7] + wvA[2 + m][7]) * 0.5f};
    }
#pragma unroll
    for (int m = 0; m < 2; ++m) {
        float* ov = out_val + egB * 64 + (c4 + 4 * m) * 8;
        *reinterpret_cast<f32x4*>(ov) =
            (f32x4){(wvB[m][0] + wvB[2 + m][0]) * 0.5f, (wvB[m][1] + wvB[2 + m][1]) * 0.5f,
                    (wvB[m][2] + wvB[2 + m][2]) * 0.5f, (wvB[m][3] + wvB[2 + m][3]) * 0.5f};
        *reinterpret_cast<f32x4*>(ov + 4) =
            (f32x4){(wvB[m][4] + wvB[2 + m][4]) * 0.5f, (wvB[m][5] + wvB[2 + m][5]) * 0.5f,
                    (wvB[m][6] + wvB[2 + m][6]) * 0.5f, (wvB[m][7] + wvB[2 + m][7]) * 0.5f};
    }
}

extern "C" void kernel_launch(void* const* d_in, const int* in_sizes, int n_in,
                              void* d_out, int out_size, void* d_ws, size_t ws_size,
                              hipStream_t stream) {
    const float* x   = (const float*)d_in[0];
    const float* hw  = (const float*)d_in[1];
    const float* lsh = (const float*)d_in[2];
    const void*  rnd = (const void*)d_in[3];

    float* out_idx = (float*)d_out;
    float* out_val = out_idx + (size_t)BATCH * 128;

    lma_mfmaB<<<2048, 512, 0, stream>>>(x, hw, lsh, rnd, out_idx, out_val);
}

// Round 21
// 251.578 us; speedup vs baseline: 1.0884x; 1.0884x over previous
//
#include <hip/hip_runtime.h>
#include <stdint.h>

typedef __attribute__((ext_vector_type(8))) short short8;
typedef __attribute__((ext_vector_type(4))) float f32x4;

constexpr int      BATCH    = 524288;
constexpr int      ARRAY_SZ = 262144;
constexpr uint64_t PRIME    = 2038074743ull;
constexpr uint32_t RANGE    = 262137u;          // ARRAY_SZ - 8 + 1
constexpr int      NMT      = BATCH / 16;       // 32768 M-tiles of 16 elements
// Sign-certainty bound, 2-split (hi+mid) MFMA vs sequential-fmaf reference
// (derivation r17, verified absmax 0.0 r17-r20): total error < 5.4e-5 *
// Sum|x|, margin EPS = 8e-5. Flagged entries recomputed with the sequential
// fmaf chain proven bit-exact in rounds 1-20.
constexpr float    EPS      = 8e-5f;

__device__ __forceinline__ void load_hash_consts(const void* rnd_raw,
                                                 uint64_t& HA, uint64_t& HB, uint64_t& HC0)
{
    const uint64_t first8 = *reinterpret_cast<const uint64_t*>(rnd_raw);
    if (first8 == PRIME) {
        const long long* r64 = reinterpret_cast<const long long*>(rnd_raw);
        HA = (uint64_t)r64[1]; HB = (uint64_t)r64[2]; HC0 = (uint64_t)r64[3];
    } else {
        const int* r32 = reinterpret_cast<const int*>(rnd_raw);
        HA  = (uint64_t)(uint32_t)r32[1];
        HB  = (uint64_t)(uint32_t)r32[2];
        HC0 = (uint64_t)(uint32_t)r32[3];
    }
}

// ============ Kernel 1: srp records (MFMA + ballot + fallback) ============
__global__ __launch_bounds__(256, 2)
void lma_srp(const float* __restrict__ x,
             const float* __restrict__ lsh,
             const void* __restrict__ rnd_raw,
             uint32_t* __restrict__ rec_out)   // BATCH*4 dwords (16B/element)
{
    __shared__ unsigned short T[128 * 128];   // lsh^T bf16, XOR-swizzled

    const int tid  = threadIdx.x;
    const int lane = tid & 63;
    const int wid  = __builtin_amdgcn_readfirstlane(tid >> 6);

    for (int it = 0; it < 16; ++it) {
        const int flat4 = it * 256 + tid;
        const int i  = flat4 >> 5;
        const int n4 = (flat4 & 31) << 2;
        const f32x4 v = *reinterpret_cast<const f32x4*>(lsh + i * 128 + n4);
#pragma unroll
        for (int d = 0; d < 4; ++d) {
            const int n = n4 + d;
            T[n * 128 + (((i >> 3) ^ (n & 15)) << 3) + (i & 7)] =
                (unsigned short)(__float_as_uint(v[d]) >> 16);
        }
    }
    __syncthreads();

    const int r    = lane & 15;
    const int g    = lane >> 4;
    const int e    = lane >> 2;
    const int c4   = lane & 3;
    const int hf   = c4 & 1;
    const int npar = c4 >> 1;
    const int shb  = 16 * (e >> 2) + 8 * hf;
    const int sel  = e & 3;
    const bool s0 = (sel == 0), s1 = (sel == 1), s2 = (sel == 2);

    const int mt0 = blockIdx.x * 4 + wid;            // grid 2048 -> stride 8192
    f32x4 xp0, xp1, xp2, xp3, xp4, xp5, xp6, xp7;
    {
        const float* xn = x + (size_t)mt0 * 16 * 128 + r * 128 + g * 8;
        xp0 = *reinterpret_cast<const f32x4*>(xn);
        xp1 = *reinterpret_cast<const f32x4*>(xn + 4);
        xp2 = *reinterpret_cast<const f32x4*>(xn + 32);
        xp3 = *reinterpret_cast<const f32x4*>(xn + 36);
        xp4 = *reinterpret_cast<const f32x4*>(xn + 64);
        xp5 = *reinterpret_cast<const f32x4*>(xn + 68);
        xp6 = *reinterpret_cast<const f32x4*>(xn + 96);
        xp7 = *reinterpret_cast<const f32x4*>(xn + 100);
    }

#pragma unroll 1
    for (int mt = mt0; mt < NMT; mt += 8192) {
        const int Mb = mt * 16;

        f32x4 acc[8];
#pragma unroll
        for (int n8 = 0; n8 < 8; ++n8) acc[n8] = (f32x4)(0.0f);
        float asum = 0.0f;

#pragma unroll
        for (int ks = 0; ks < 4; ++ks) {
            const f32x4 xa = (ks == 0) ? xp0 : (ks == 1) ? xp2 : (ks == 2) ? xp4 : xp6;
            const f32x4 xc = (ks == 0) ? xp1 : (ks == 1) ? xp3 : (ks == 2) ? xp5 : xp7;
            float xs[8] = {xa[0], xa[1], xa[2], xa[3], xc[0], xc[1], xc[2], xc[3]};
#pragma unroll
            for (int j = 0; j < 8; ++j) asum += fabsf(xs[j]);

            union { uint32_t u[4]; short8 v; } Ahi, Ami;
#pragma unroll
            for (int p = 0; p < 4; ++p) {
                const uint32_t b0 = __float_as_uint(xs[2 * p]);
                const uint32_t b1 = __float_as_uint(xs[2 * p + 1]);
                const uint32_t h0 = b0 & 0xFFFF0000u, h1 = b1 & 0xFFFF0000u;
                const float    t0 = xs[2 * p] - __uint_as_float(h0);
                const float    t1 = xs[2 * p + 1] - __uint_as_float(h1);
                const uint32_t m0 = __float_as_uint(t0) & 0xFFFF0000u;
                const uint32_t m1 = __float_as_uint(t1) & 0xFFFF0000u;
                Ahi.u[p] = h1 | (h0 >> 16);
                Ami.u[p] = m1 | (m0 >> 16);
            }
#pragma unroll
            for (int n8 = 0; n8 < 8; ++n8) {
                const short8 bf = *reinterpret_cast<const short8*>(
                    &T[(n8 * 16 + r) * 128 + (((ks * 4 + g) ^ r) << 3)]);
                acc[n8] = __builtin_amdgcn_mfma_f32_16x16x32_bf16(Ahi.v, bf, acc[n8], 0, 0, 0);
                acc[n8] = __builtin_amdgcn_mfma_f32_16x16x32_bf16(Ami.v, bf, acc[n8], 0, 0, 0);
            }
        }

        {
            const int mtn = (mt + 8192 < NMT) ? mt + 8192 : mt;
            const float* xn = x + (size_t)mtn * 16 * 128 + r * 128 + g * 8;
            xp0 = *reinterpret_cast<const f32x4*>(xn);
            xp1 = *reinterpret_cast<const f32x4*>(xn + 4);
            xp2 = *reinterpret_cast<const f32x4*>(xn + 32);
            xp3 = *reinterpret_cast<const f32x4*>(xn + 36);
            xp4 = *reinterpret_cast<const f32x4*>(xn + 64);
            xp5 = *reinterpret_cast<const f32x4*>(xn + 68);
            xp6 = *reinterpret_cast<const f32x4*>(xn + 96);
            xp7 = *reinterpret_cast<const f32x4*>(xn + 100);
        }
        __builtin_amdgcn_sched_barrier(0);

        asum += __shfl_xor(asum, 16);
        asum += __shfl_xor(asum, 32);
        float bndr[4];
#pragma unroll
        for (int reg = 0; reg < 4; ++reg)
            bndr[reg] = __shfl(asum, (lane >> 4) * 4 + reg) * EPS;

        uint32_t wsrp = 0, wflg = 0;
#pragma unroll
        for (int n8 = 0; n8 < 8; ++n8) {
            const unsigned long long sb0 = __ballot(acc[n8][0] > 0.0f);
            const unsigned long long sb1 = __ballot(acc[n8][1] > 0.0f);
            const unsigned long long sb2 = __ballot(acc[n8][2] > 0.0f);
            const unsigned long long sb3 = __ballot(acc[n8][3] > 0.0f);
            const unsigned long long fb0 = __ballot(fabsf(acc[n8][0]) <= bndr[0]);
            const unsigned long long fb1 = __ballot(fabsf(acc[n8][1]) <= bndr[1]);
            const unsigned long long fb2 = __ballot(fabsf(acc[n8][2]) <= bndr[2]);
            const unsigned long long fb3 = __ballot(fabsf(acc[n8][3]) <= bndr[3]);
            const unsigned long long sbx = s0 ? sb0 : s1 ? sb1 : s2 ? sb2 : sb3;
            const unsigned long long fbx = s0 ? fb0 : s1 ? fb1 : s2 ? fb2 : fb3;
            if ((n8 & 1) == npar) {
                const int mshift = ((n8 - npar) >> 1) * 8;
                wsrp |= (uint32_t)((sbx >> shb) & 0xffull) << mshift;
                wflg |= (uint32_t)((fbx >> shb) & 0xffull) << mshift;
            }
        }

        const size_t eg = (size_t)(Mb + e);
        // resolve uncertain signs exactly (rare), then store the 4-byte record
        if (wflg) {
            const float* xr = x + eg * 128;
            for (uint32_t fb = wflg; fb; fb &= fb - 1) {
                const int bit = __builtin_ctz(fb);        // 8*m + j
                const int m   = bit >> 3;
                const int j   = bit & 7;
                const int k   = (c4 + 4 * m) * 8 + j;
                float s = 0.0f;
#pragma unroll 4
                for (int i8 = 0; i8 < 16; ++i8) {
                    const uint4 tb = *reinterpret_cast<const uint4*>(
                        &T[k * 128 + ((i8 ^ (k & 15)) << 3)]);
                    const f32x4 xA = *reinterpret_cast<const f32x4*>(xr + i8 * 8);
                    const f32x4 xB = *reinterpret_cast<const f32x4*>(xr + i8 * 8 + 4);
                    const uint32_t tu[4] = {tb.x, tb.y, tb.z, tb.w};
                    s = __builtin_fmaf(xA[0], __uint_as_float(tu[0] << 16), s);
                    s = __builtin_fmaf(xA[1], __uint_as_float(tu[0] & 0xFFFF0000u), s);
                    s = __builtin_fmaf(xA[2], __uint_as_float(tu[1] << 16), s);
                    s = __builtin_fmaf(xA[3], __uint_as_float(tu[1] & 0xFFFF0000u), s);
                    s = __builtin_fmaf(xB[0], __uint_as_float(tu[2] << 16), s);
                    s = __builtin_fmaf(xB[1], __uint_as_float(tu[2] & 0xFFFF0000u), s);
                    s = __builtin_fmaf(xB[2], __uint_as_float(tu[3] << 16), s);
                    s = __builtin_fmaf(xB[3], __uint_as_float(tu[3] & 0xFFFF0000u), s);
                }
                wsrp = (wsrp & ~(1u << bit)) | ((s > 0.0f) ? (1u << bit) : 0u);
            }
        }
        rec_out[eg * 4 + c4] = wsrp;   // wave writes 16 elem x 16B contiguous
    }
}

// ============ Kernel 2: hash + gather + stores (streaming, no LDS) ============
__global__ __launch_bounds__(256, 8)
void lma_emit(const float* __restrict__ hw,
              const uint32_t* __restrict__ rec,
              const void* __restrict__ rnd_raw,
              float* __restrict__ out_idx,
              float* __restrict__ out_val)
{
    uint64_t HA, HB, HC0;
    load_hash_consts(rnd_raw, HA, HB, HC0);

    const int gtid = blockIdx.x * 256 + threadIdx.x;   // BATCH*16 tasks
    const int e    = gtid >> 4;
    const int cc   = gtid & 15;
    const int cch  = cc & 7;
    const int rep  = cc >> 3;

    const uint4 rv = *reinterpret_cast<const uint4*>(rec + (size_t)e * 4);
    const int compo = cc & 3;
    const uint32_t dw = (compo == 0) ? rv.x : (compo == 1) ? rv.y
                      : (compo == 2) ? rv.z : rv.w;
    const uint32_t srp = (dw >> (8 * (cc >> 2))) & 0xFFu;

    const uint64_t hh  = (HA * (uint64_t)srp + HB * (uint64_t)cch + HC0) % PRIME;
    const uint32_t loc = (uint32_t)hh % RANGE + (rep ? (uint32_t)ARRAY_SZ : 0u);

    const float f0 = (float)loc;
    float* oi = out_idx + (size_t)e * 128 + cc * 8;
    *reinterpret_cast<f32x4*>(oi)     = (f32x4){f0, f0 + 1.f, f0 + 2.f, f0 + 3.f};
    *reinterpret_cast<f32x4*>(oi + 4) = (f32x4){f0 + 4.f, f0 + 5.f, f0 + 6.f, f0 + 7.f};

    float wv[8];
#pragma unroll
    for (int j = 0; j < 8; ++j) wv[j] = hw[loc + j];

    // rep partner (cc^8) is lane^8: one shuffle averages both reps
    float v[8];
#pragma unroll
    for (int j = 0; j < 8; ++j)
        v[j] = (wv[j] + __shfl_xor(wv[j], 8)) * 0.5f;

    if (rep == 0) {
        float* ov = out_val + (size_t)e * 64 + cc * 8;
        *reinterpret_cast<f32x4*>(ov)     = (f32x4){v[0], v[1], v[2], v[3]};
        *reinterpret_cast<f32x4*>(ov + 4) = (f32x4){v[4], v[5], v[6], v[7]};
    }
}

extern "C" void kernel_launch(void* const* d_in, const int* in_sizes, int n_in,
                              void* d_out, int out_size, void* d_ws, size_t ws_size,
                              hipStream_t stream) {
    const float* x   = (const float*)d_in[0];
    const float* hw  = (const float*)d_in[1];
    const float* lsh = (const float*)d_in[2];
    const void*  rnd = (const void*)d_in[3];

    float*    out_idx = (float*)d_out;
    float*    out_val = out_idx + (size_t)BATCH * 128;
    uint32_t* recbuf  = (uint32_t*)d_ws;              // BATCH*16 B = 8.4 MB

    lma_srp <<<2048, 256, 0, stream>>>(x, lsh, rnd, recbuf);
    lma_emit<<<BATCH * 16 / 256, 256, 0, stream>>>(hw, recbuf, rnd, out_idx, out_val);
}